// Round 6
// baseline (240.977 us; speedup 1.0000x reference)
//
#include <hip/hip_runtime.h>
#include <stdint.h>

// pooled[b,p] = sum_{n in seg b} max_e ( proxy[p,e,:] . x[n,:] );  out = L2-normalized rows.
// P=128, E=32, D=64, B=1024 segments. Ragged handled via zeroed-B masking.
//
// R5 = R4's e-loop running-max dataflow with a spill-proof register budget:
//  - wave = p-group g (32 rows) x 2 n-tiles; the block's 4 tiles are covered by
//    two sequential tile-pair phases (tp=0,1). Inner e-step: 8 MFMAs + 32 v_max,
//    NO cross-lane/LDS ops. Budget: M 32 + d 32 + bfrag 32 + A-dbuf 32 + zc 16
//    + misc ~= 164 VGPR -> __launch_bounds__(256,3): 3 waves/SIMD, no AGPR split,
//    no scratch (R4 spilled: WRITE_SIZE 45 MB, 128V+128A split).
//  - A (proxy) fragment-major bf16 (frag = contiguous 1KB, lane*16B slots),
//    double-buffered prefetch of e+1.
//  - reductions (tile-sum, col-sum, L2-normalize) once per phase via LDS.

typedef short short8 __attribute__((ext_vector_type(8)));
typedef __bf16 bf16x8 __attribute__((ext_vector_type(8)));
typedef float floatx16 __attribute__((ext_vector_type(16)));

#define NELEM 32
#define DIM   64
#define NSEG  1024
#define BROW  36   /* buf row stride (floats): 32 cols + 4 pad; 16B-aligned rows */

__device__ __forceinline__ unsigned short f32_to_bf16_rne(float f) {
  union { float f; unsigned int u; } v; v.f = f;
  unsigned int r = v.u + 0x7fffu + ((v.u >> 16) & 1u);
  return (unsigned short)(r >> 16);
}

// Block 0: exclusive scan of segment lengths -> offs[0..NSEG].
// Blocks 1..128: proxy fp32 -> fragment-major bf16 pa2.
//   task f = g*128 + e*4 + kk (g = p>>5): frag at pa2 + f*512 shorts, lane slot
//   = +lane*8; source: proxy[g*32 + (lane&31)][e][kk*16 + (lane>>5)*8 .. +8]
__global__ void sc_prep(const float* __restrict__ proxy,
                        const int* __restrict__ index,
                        short* __restrict__ pa2,
                        int* __restrict__ offs) {
  const int bx = blockIdx.x, t = threadIdx.x;
  if (bx == 0) {
    __shared__ int lsum[256];
    const int base = t * 4;
    const int i0 = index[base + 0], i1 = index[base + 1];
    const int i2 = index[base + 2], i3 = index[base + 3];
    const int s = i0 + i1 + i2 + i3;
    lsum[t] = s;
    __syncthreads();
    for (int off = 1; off < 256; off <<= 1) {
      int v = (t >= off) ? lsum[t - off] : 0;
      __syncthreads();
      lsum[t] += v;
      __syncthreads();
    }
    const int ex = lsum[t] - s;
    offs[base + 0] = ex;
    offs[base + 1] = ex + i0;
    offs[base + 2] = ex + i0 + i1;
    offs[base + 3] = ex + i0 + i1 + i2;
    if (t == 255) offs[NSEG] = ex + s;
  } else {
    const int wv = t >> 6, lane = t & 63;
    const int f = (bx - 1) * 4 + wv;         // 0..511
    const int g = f >> 7, e = (f >> 2) & 31, kk = f & 3;
    const int l31 = lane & 31, h = lane >> 5;
    const float* src = proxy + ((size_t)(g * 32 + l31) * NELEM + e) * DIM + kk * 16 + h * 8;
    float4 f0 = *(const float4*)(src);
    float4 f1 = *(const float4*)(src + 4);
    short8 fr;
    fr[0] = (short)f32_to_bf16_rne(f0.x);
    fr[1] = (short)f32_to_bf16_rne(f0.y);
    fr[2] = (short)f32_to_bf16_rne(f0.z);
    fr[3] = (short)f32_to_bf16_rne(f0.w);
    fr[4] = (short)f32_to_bf16_rne(f1.x);
    fr[5] = (short)f32_to_bf16_rne(f1.y);
    fr[6] = (short)f32_to_bf16_rne(f1.z);
    fr[7] = (short)f32_to_bf16_rne(f1.w);
    *(short8*)(pa2 + ((size_t)f * 64 + lane) * 8) = fr;  // coalesced 1KB/wave
  }
}

__global__ __launch_bounds__(256, 3) void sc_main(
    const float* __restrict__ x,
    const short* __restrict__ pa2,
    const int* __restrict__ offs,
    float* __restrict__ out,
    int nrows) {
  __shared__ float buf[128 * BROW];  // [p][col]: per-column partial sums
  __shared__ float red[4];

  const int b = blockIdx.x;
  const int tid = threadIdx.x;
  const int lane = tid & 63;
  const int g = tid >> 6;   // p-group: rows p = g*32 + 0..31
  const int l31 = lane & 31;
  const int h = lane >> 5;

  const int start = offs[b];
  const int end = offs[b + 1];
  const int len = end - start;
  const int first = start >> 5;
  const int ntiles = (len > 0) ? (((end + 31) >> 5) - first) : 0;
  const int npass = (ntiles + 3) >> 2;

  if (ntiles == 0) {
    for (int j = tid; j < 128 * BROW; j += 256) buf[j] = 0.f;
  }

  floatx16 zc;  // permanently-zero C operand (no per-chain acc init)
#pragma unroll
  for (int r = 0; r < 16; ++r) zc[r] = 0.f;

  // frag(g,e,kk) at pa2 + (g*128 + e*4 + kk)*512 + lane*8 shorts
  const short* abase = pa2 + (size_t)g * (128 * 512) + lane * 8;

  for (int pass = 0; pass < npass; ++pass) {
    for (int tp = 0; tp < 2; ++tp) {
      // B-frags: this phase's 2 n-tiles, fp32 -> bf16 in-reg.
      // Invalid columns ZEROED -> D=0 for every e -> running max = 0 -> adds 0.
      short8 bfrag[2][4];
#pragma unroll
      for (int t2 = 0; t2 < 2; ++t2) {
        const int n = (first + pass * 4 + tp * 2 + t2) * 32 + l31;
        const bool valid = (n >= start) && (n < end) && (n < nrows);
        const float* xr = x + (size_t)(valid ? n : 0) * DIM + h * 8;
#pragma unroll
        for (int kk = 0; kk < 4; ++kk) {
          float4 f0 = make_float4(0.f, 0.f, 0.f, 0.f), f1 = f0;
          if (valid) {
            f0 = *(const float4*)(xr + kk * 16);
            f1 = *(const float4*)(xr + kk * 16 + 4);
          }
          short8 fr;
          fr[0] = (short)f32_to_bf16_rne(f0.x);
          fr[1] = (short)f32_to_bf16_rne(f0.y);
          fr[2] = (short)f32_to_bf16_rne(f0.z);
          fr[3] = (short)f32_to_bf16_rne(f0.w);
          fr[4] = (short)f32_to_bf16_rne(f1.x);
          fr[5] = (short)f32_to_bf16_rne(f1.y);
          fr[6] = (short)f32_to_bf16_rne(f1.z);
          fr[7] = (short)f32_to_bf16_rne(f1.w);
          bfrag[t2][kk] = fr;
        }
      }

      // Running max over e, per tile, in MFMA C-layout registers.
      floatx16 M0, M1;
#pragma unroll
      for (int r = 0; r < 16; ++r) { M0[r] = -3.0e38f; M1[r] = -3.0e38f; }

      auto estep = [&](const short8 (&cur)[4], short8 (&nxt)[4], int enext, bool pf) {
        if (pf) {  // coalesced A prefetch for next e (4KB/wave)
          const short* ap = abase + (size_t)enext * 2048;
#pragma unroll
          for (int kk = 0; kk < 4; ++kk)
            nxt[kk] = *(const short8*)(ap + kk * 512);
        }
        floatx16 d0, d1;  // 2 independent MFMA chains
#pragma unroll
        for (int kk = 0; kk < 4; ++kk) {
          bf16x8 a = __builtin_bit_cast(bf16x8, cur[kk]);
          bf16x8 b0 = __builtin_bit_cast(bf16x8, bfrag[0][kk]);
          bf16x8 b1 = __builtin_bit_cast(bf16x8, bfrag[1][kk]);
          if (kk == 0) {
            d0 = __builtin_amdgcn_mfma_f32_32x32x16_bf16(a, b0, zc, 0, 0, 0);
            d1 = __builtin_amdgcn_mfma_f32_32x32x16_bf16(a, b1, zc, 0, 0, 0);
          } else {
            d0 = __builtin_amdgcn_mfma_f32_32x32x16_bf16(a, b0, d0, 0, 0, 0);
            d1 = __builtin_amdgcn_mfma_f32_32x32x16_bf16(a, b1, d1, 0, 0, 0);
          }
        }
#pragma unroll
        for (int r = 0; r < 16; ++r) {
          M0[r] = fmaxf(M0[r], d0[r]);
          M1[r] = fmaxf(M1[r], d1[r]);
        }
      };

      short8 aA[4], aB[4];
#pragma unroll
      for (int kk = 0; kk < 4; ++kk)
        aA[kk] = *(const short8*)(abase + kk * 512);
      for (int e = 0; e < 32; e += 2) {  // unroll-2: compile-time dbuf index
        estep(aA, aB, e + 1, true);
        estep(aB, aA, e + 2, e < 30);
      }

      // Phase epilogue: tile-pair sum in C-layout, 16 LDS adds per lane.
      // row r -> p = g*32 + (r&3) + 8*(r>>2) + 4*h ; col = l31. (2-way = free)
      const bool firstw = (pass == 0) && (tp == 0);
#pragma unroll
      for (int r = 0; r < 16; ++r) {
        const float s = M0[r] + M1[r];
        const int p = g * 32 + (r & 3) + 8 * (r >> 2) + 4 * h;
        const int idx = p * BROW + l31;
        const float prev = firstw ? 0.f : buf[idx];
        buf[idx] = prev + s;
      }
    }
  }
  __syncthreads();

  // Batched 32-col reduction + fused L2-normalize. 2 threads per p.
  const int p2 = tid >> 1, part = tid & 1;
  const float* bp = buf + p2 * BROW + part * 16;
  float4 v0 = *(const float4*)(bp + 0);
  float4 v1 = *(const float4*)(bp + 4);
  float4 v2 = *(const float4*)(bp + 8);
  float4 v3 = *(const float4*)(bp + 12);
  float s16 = ((v0.x + v0.y) + (v0.z + v0.w)) + ((v1.x + v1.y) + (v1.z + v1.w)) +
              ((v2.x + v2.y) + (v2.z + v2.w)) + ((v3.x + v3.y) + (v3.z + v3.w));
  const float s32 = s16 + __shfl_xor(s16, 1, 64);  // pooled[b][p2]

  float sq = part ? 0.f : s32 * s32;
#pragma unroll
  for (int off = 1; off <= 32; off <<= 1) sq += __shfl_xor(sq, off, 64);
  if (lane == 0) red[tid >> 6] = sq;
  __syncthreads();
  const float ss = (red[0] + red[1]) + (red[2] + red[3]);
  const float inv = 1.f / fmaxf(sqrtf(ss), 1e-12f);
  if (part == 0) out[(b << 7) + p2] = s32 * inv;
}

extern "C" void kernel_launch(void* const* d_in, const int* in_sizes, int n_in,
                              void* d_out, int out_size, void* d_ws, size_t ws_size,
                              hipStream_t stream) {
  (void)n_in; (void)out_size; (void)ws_size;
  const float* x = (const float*)d_in[0];      // [N, 64] fp32
  const float* proxy = (const float*)d_in[1];  // [128, 32, 64] fp32
  const int* index = (const int*)d_in[2];      // [1024] int32
  float* out = (float*)d_out;                  // [1024, 128] fp32
  const int nrows = in_sizes[0] / DIM;

  int* offs = (int*)d_ws;                      // (NSEG+1) ints
  short* pa2 = (short*)((char*)d_ws + 8192);   // 512 KB fragment-major bf16 proxy

  sc_prep<<<129, 256, 0, stream>>>(proxy, index, pa2, offs);
  sc_main<<<NSEG, 256, 0, stream>>>(x, pa2, offs, out, nrows);
}

// Round 7
// 139.747 us; speedup vs baseline: 1.7244x; 1.7244x over previous
//
#include <hip/hip_runtime.h>
#include <stdint.h>

// pooled[b,p] = sum_{n in seg b} max_e ( proxy[p,e,:] . x[n,:] );  out = L2-normalized rows.
// P=128, E=32, D=64, B=1024 segments. Ragged handled via zeroed-B masking.
//
// R6 = round-4's best structure (2-chain waves, frag-major A, zero-C, (256,2))
// plus two structural changes:
//  - block = 2 SEGMENTS (grid 512): wave (ws,wt) = segment ws, tile-pair wt;
//    every wave loops ALL 128 p -> the 4 waves share one frag(p) stream
//    (1 L2 read + 3 L1 hits), chip A-traffic halves to 256 MB.
//  - per-iteration LDS accumulate is a fire-and-forget ds_add_f32 (atomicAdd on
//    shared): no LDS read in the dependency chain; buf folds the wt dimension
//    (2 x 128 x 36 floats = 37 KB).
// NO launch_bounds squeeze (R5's (256,3) spilled 228 MB to scratch).

typedef short short8 __attribute__((ext_vector_type(8)));
typedef __bf16 bf16x8 __attribute__((ext_vector_type(8)));
typedef float floatx16 __attribute__((ext_vector_type(16)));

#define NELEM 32
#define DIM   64
#define NSEG  1024
#define BROW  36   /* buf row stride (floats): 32 cols + 4 pad */

__device__ __forceinline__ unsigned short f32_to_bf16_rne(float f) {
  union { float f; unsigned int u; } v; v.f = f;
  unsigned int r = v.u + 0x7fffu + ((v.u >> 16) & 1u);
  return (unsigned short)(r >> 16);
}

// Block 0: exclusive scan of segment lengths -> offs[0..NSEG].
// Blocks 1..128: proxy fp32 -> fragment-major bf16 pb2:
//   frag(p,kk) = contiguous 1KB at (p*4+kk)*512 shorts; lane slot = +lane*8.
__global__ void sc_prep(const float* __restrict__ proxy,
                        const int* __restrict__ index,
                        short* __restrict__ pb2,
                        int* __restrict__ offs) {
  const int bx = blockIdx.x, t = threadIdx.x;
  if (bx == 0) {
    __shared__ int lsum[256];
    const int base = t * 4;
    const int i0 = index[base + 0], i1 = index[base + 1];
    const int i2 = index[base + 2], i3 = index[base + 3];
    const int s = i0 + i1 + i2 + i3;
    lsum[t] = s;
    __syncthreads();
    for (int off = 1; off < 256; off <<= 1) {
      int v = (t >= off) ? lsum[t - off] : 0;
      __syncthreads();
      lsum[t] += v;
      __syncthreads();
    }
    const int ex = lsum[t] - s;
    offs[base + 0] = ex;
    offs[base + 1] = ex + i0;
    offs[base + 2] = ex + i0 + i1;
    offs[base + 3] = ex + i0 + i1 + i2;
    if (t == 255) offs[NSEG] = ex + s;
  } else {
    const int w = t >> 6, lane = t & 63;
    const int task = (bx - 1) * 4 + w;   // 0..511 = (p, kk)
    const int p = task >> 2, kk = task & 3;
    const int l31 = lane & 31, h = lane >> 5;
    const float* src = proxy + (size_t)p * (NELEM * DIM) + l31 * DIM + kk * 16 + h * 8;
    float4 f0 = *(const float4*)(src);
    float4 f1 = *(const float4*)(src + 4);
    short8 fr;
    fr[0] = (short)f32_to_bf16_rne(f0.x);
    fr[1] = (short)f32_to_bf16_rne(f0.y);
    fr[2] = (short)f32_to_bf16_rne(f0.z);
    fr[3] = (short)f32_to_bf16_rne(f0.w);
    fr[4] = (short)f32_to_bf16_rne(f1.x);
    fr[5] = (short)f32_to_bf16_rne(f1.y);
    fr[6] = (short)f32_to_bf16_rne(f1.z);
    fr[7] = (short)f32_to_bf16_rne(f1.w);
    *(short8*)(pb2 + ((size_t)task * 64 + lane) * 8) = fr;  // coalesced 1KB/wave
  }
}

__device__ __forceinline__ float max16(const floatx16& a) {
  float r0 = fmaxf(fmaxf(a[0], a[1]), a[2]);
  float r1 = fmaxf(fmaxf(a[3], a[4]), a[5]);
  float r2 = fmaxf(fmaxf(a[6], a[7]), a[8]);
  float r3 = fmaxf(fmaxf(a[9], a[10]), a[11]);
  float r4 = fmaxf(fmaxf(a[12], a[13]), a[14]);
  float r5 = fmaxf(fmaxf(r0, r1), r2);
  float r6 = fmaxf(fmaxf(r3, r4), a[15]);
  return fmaxf(r5, r6);
}

__global__ __launch_bounds__(256, 2) void sc_main(
    const float* __restrict__ x,
    const short* __restrict__ pb2,
    const int* __restrict__ offs,
    float* __restrict__ out,
    int nrows) {
  __shared__ float buf[2 * 128 * BROW];  // [ws][p][col]: ds_add_f32 accumulated
  __shared__ float red[4];

  const int b = blockIdx.x;              // 0..511: segments 2b, 2b+1
  const int tid = threadIdx.x;
  const int lane = tid & 63;
  const int w = tid >> 6;
  const int ws = w >> 1;                 // segment select
  const int wt = w & 1;                  // tile-pair select (cols wt*64..wt*64+63)
  const int l31 = lane & 31;
  const int h = lane >> 5;

  const int s0 = offs[2 * b + ws];
  const int e0 = offs[2 * b + ws + 1];
  const int len = e0 - s0;
  const int npass = (len > 0) ? ((len + 127) >> 7) : 0;  // waves loop independently

  for (int j = tid; j < 2 * 128 * BROW; j += 256) buf[j] = 0.f;
  __syncthreads();

  floatx16 zc;  // permanently-zero C operand (no per-p acc init)
#pragma unroll
  for (int r = 0; r < 16; ++r) zc[r] = 0.f;

  // frag(p,kk) at pb2 + (p*4+kk)*512 + lane*8 shorts; p-stride = 2048 shorts
  const short* abase = pb2 + lane * 8;
  float* const brow = buf + ws * 128 * BROW;  // this segment's accumulator

  for (int pass = 0; pass < npass; ++pass) {
    // B-frags: this wave's 2 tiles of its segment, fp32 -> bf16 in-reg.
    // Invalid columns ZEROED (max_e(0)=0 adds nothing).
    short8 bfrag[2][4];
#pragma unroll
    for (int t2 = 0; t2 < 2; ++t2) {
      const int n = s0 + pass * 128 + wt * 64 + t2 * 32 + l31;
      const bool valid = (n < e0) && (n < nrows);
      const float* xr = x + (size_t)(valid ? n : 0) * DIM + h * 8;
#pragma unroll
      for (int kk = 0; kk < 4; ++kk) {
        float4 f0 = make_float4(0.f, 0.f, 0.f, 0.f), f1 = f0;
        if (valid) {
          f0 = *(const float4*)(xr + kk * 16);
          f1 = *(const float4*)(xr + kk * 16 + 4);
        }
        short8 fr;
        fr[0] = (short)f32_to_bf16_rne(f0.x);
        fr[1] = (short)f32_to_bf16_rne(f0.y);
        fr[2] = (short)f32_to_bf16_rne(f0.z);
        fr[3] = (short)f32_to_bf16_rne(f0.w);
        fr[4] = (short)f32_to_bf16_rne(f1.x);
        fr[5] = (short)f32_to_bf16_rne(f1.y);
        fr[6] = (short)f32_to_bf16_rne(f1.z);
        fr[7] = (short)f32_to_bf16_rne(f1.w);
        bfrag[t2][kk] = fr;
      }
    }

    auto process = [&](int p, short8 (&cur)[4], short8 (&nxt)[4], bool pf) {
      if (pf) {  // depth-1 coalesced A prefetch (4 waves share -> L1 hits)
        const short* ap = abase + (size_t)(p + 1) * 2048;
#pragma unroll
        for (int kk = 0; kk < 4; ++kk)
          nxt[kk] = *(const short8*)(ap + kk * 512);
      }
      floatx16 d0, d1;  // 2 independent MFMA chains
#pragma unroll
      for (int kk = 0; kk < 4; ++kk) {
        bf16x8 a = __builtin_bit_cast(bf16x8, cur[kk]);
        bf16x8 b0 = __builtin_bit_cast(bf16x8, bfrag[0][kk]);
        bf16x8 b1 = __builtin_bit_cast(bf16x8, bfrag[1][kk]);
        if (kk == 0) {
          d0 = __builtin_amdgcn_mfma_f32_32x32x16_bf16(a, b0, zc, 0, 0, 0);
          d1 = __builtin_amdgcn_mfma_f32_32x32x16_bf16(a, b1, zc, 0, 0, 0);
        } else {
          d0 = __builtin_amdgcn_mfma_f32_32x32x16_bf16(a, b0, d0, 0, 0, 0);
          d1 = __builtin_amdgcn_mfma_f32_32x32x16_bf16(a, b1, d1, 0, 0, 0);
        }
      }
      // max over e: 16 in-lane rows + complementary 16 from lane^32
      float m0 = max16(d0), m1 = max16(d1);
      m0 = fmaxf(m0, __shfl_xor(m0, 32, 64));
      m1 = fmaxf(m1, __shfl_xor(m1, 32, 64));
      const float s = m0 + m1;  // sum over this wave's 2 tiles, col l31
      if (h == 0)               // halves identical; fire-and-forget LDS atomic
        atomicAdd(&brow[p * BROW + l31], s);
    };

    short8 aA[4], aB[4];
#pragma unroll
    for (int kk = 0; kk < 4; ++kk)
      aA[kk] = *(const short8*)(abase + kk * 512);
    for (int p = 0; p < 128; p += 2) {  // all 128 p; unroll-2 dbuf
      process(p, aA, aB, true);
      process(p + 1, aB, aA, p < 126);
    }
  }
  __syncthreads();

  // Final: thread tid -> (ws2 = tid>>7, p = tid&127) == buf row tid.
  const float* bp = buf + tid * BROW;
  float4 v0 = *(const float4*)(bp + 0);
  float4 v1 = *(const float4*)(bp + 4);
  float4 v2 = *(const float4*)(bp + 8);
  float4 v3 = *(const float4*)(bp + 12);
  float4 v4 = *(const float4*)(bp + 16);
  float4 v5 = *(const float4*)(bp + 20);
  float4 v6 = *(const float4*)(bp + 24);
  float4 v7 = *(const float4*)(bp + 28);
  const float s32 =
      (((v0.x + v0.y) + (v0.z + v0.w)) + ((v1.x + v1.y) + (v1.z + v1.w))) +
      (((v2.x + v2.y) + (v2.z + v2.w)) + ((v3.x + v3.y) + (v3.z + v3.w))) +
      (((v4.x + v4.y) + (v4.z + v4.w)) + ((v5.x + v5.y) + (v5.z + v5.w))) +
      (((v6.x + v6.y) + (v6.z + v6.w)) + ((v7.x + v7.y) + (v7.z + v7.w)));

  // L2-normalize per output row (128 p = 2 waves share a row via red[]).
  float sq = s32 * s32;
#pragma unroll
  for (int off = 1; off <= 32; off <<= 1) sq += __shfl_xor(sq, off, 64);
  if (lane == 0) red[w] = sq;
  __syncthreads();
  const int ws2 = tid >> 7;
  const float ss = red[2 * ws2] + red[2 * ws2 + 1];
  const float inv = 1.f / fmaxf(sqrtf(ss), 1e-12f);
  out[(size_t)(2 * b + ws2) * 128 + (tid & 127)] = s32 * inv;
}

extern "C" void kernel_launch(void* const* d_in, const int* in_sizes, int n_in,
                              void* d_out, int out_size, void* d_ws, size_t ws_size,
                              hipStream_t stream) {
  (void)n_in; (void)out_size; (void)ws_size;
  const float* x = (const float*)d_in[0];      // [N, 64] fp32
  const float* proxy = (const float*)d_in[1];  // [128, 32, 64] fp32
  const int* index = (const int*)d_in[2];      // [1024] int32
  float* out = (float*)d_out;                  // [1024, 128] fp32
  const int nrows = in_sizes[0] / DIM;

  int* offs = (int*)d_ws;                      // (NSEG+1) ints
  short* pb2 = (short*)((char*)d_ws + 8192);   // 512 KB fragment-major bf16 proxy

  sc_prep<<<129, 256, 0, stream>>>(proxy, index, pb2, offs);
  sc_main<<<NSEG / 2, 256, 0, stream>>>(x, pb2, offs, out, nrows);
}